// Round 2
// 181.889 us; speedup vs baseline: 1.0141x; 1.0141x over previous
//
#include <hip/hip_runtime.h>
#include <hip/hip_bf16.h>

#define EPSF 1e-14f
#define RHOF 8.0f

typedef __attribute__((ext_vector_type(4))) float f32x4;
typedef __attribute__((ext_vector_type(8))) int   i32x8;
typedef __attribute__((ext_vector_type(2))) unsigned long long u64x2;

#define AS_GLOBAL __attribute__((address_space(1)))
#define AS_LDS    __attribute__((address_space(3)))

// fp8 packed layout, BK=128 (for mfma_scale 16x16x128). Tile = 128 rows x
// 128 cols fp8 = 16 KB = 1024 units of 16 B. Row r = 8 units; content unit
// u stored at slot u ^ (r&7). Fragment (quad qd) needs k-block qd*32..+31 =
// content units {2qd, 2qd+1} -> slots s0=(2qd)^(lo&7), s0^1: two
// ds_read_b128. Per 16-lane phase s0 covers 8 slots twice -> 32 banks
// 2-way (free, m136). global_load_lds deposit order == packed order.

__global__ __launch_bounds__(256) void prep_fp8(
    const float* __restrict__ im,  const float* __restrict__ tt,
    const float* __restrict__ rim, const float* __restrict__ rtt,
    unsigned char* __restrict__ bIm,  unsigned char* __restrict__ bTt,
    unsigned char* __restrict__ bRim, unsigned char* __restrict__ bRtt,
    float* __restrict__ S_im, float* __restrict__ S_tt,
    float* __restrict__ diag, float* __restrict__ red,
    int D, int spm /* 8-row slabs per matrix */)
{
    __shared__ unsigned char L[8 * 1024];   // 8 rows x D fp8 (D<=1024)
    const int b = blockIdx.x;
    const int tid = threadIdx.x;
    const int nConv = 4 * spm;
    if (b < nConv) {
        int mIdx = b / spm;
        int slab = b - mIdx * spm;
        const float* src = (mIdx == 0) ? rim : (mIdx == 1) ? tt
                          : (mIdx == 2) ? rtt : im;
        unsigned char* dst = (mIdx == 0) ? bRim : (mIdx == 1) ? bTt
                            : (mIdx == 2) ? bRtt : bIm;
        const float* srow = src + (size_t)slab * 8 * D;
        const int n4 = (8 * D) >> 2;
        for (int idx = tid; idx < n4; idx += 256) {
            float4 v = *(const float4*)(srow + idx * 4);
            int pk = __builtin_amdgcn_cvt_pk_fp8_f32(v.x, v.y, 0, false);
            pk     = __builtin_amdgcn_cvt_pk_fp8_f32(v.z, v.w, pk, true);
            *(int*)&L[idx * 4] = pk;
        }
        __syncthreads();
        const int kTiles = D >> 7;               // 128-wide k tiles
        const int rb = (slab * 8) >> 7;
        const int r0loc = (slab * 8) & 127;
        for (int g = tid; g < (D >> 1); g += 256) {  // units per slab = D/2
            int kb  = g >> 6;                    // 64 units per (slab,kb)
            int rem = g & 63;
            int rl  = rem >> 3;
            int p   = rem & 7;                   // slot position
            int r   = slab * 8 + rl;
            int c   = p ^ (r & 7);               // content unit at slot p
            const unsigned char* lb = &L[rl * D + kb * 128 + c * 16];
            u64x2 o = *(const u64x2*)lb;
            char* outp = (char*)dst
                       + ((size_t)(rb * kTiles + kb) * 1024
                          + (size_t)(r0loc + rl) * 8 + p) * 16;
            *(u64x2*)outp = o;
        }
    } else {
        int db = b - nConv;
        if (db == 0 && tid < 8) red[tid] = 0.f;
        if (tid < 4) { S_im[db * 4 + tid] = 0.f; S_tt[db * 4 + tid] = 0.f; }
        int row  = db * 4 + (tid >> 6);
        int lane = tid & 63;
        const float* a = rim + (size_t)row * D;
        const float* c = rtt + (size_t)row * D;
        float s = 0.f;
        for (int k = lane * 4; k < D; k += 256) {
            float4 av = *(const float4*)(a + k);
            float4 cv = *(const float4*)(c + k);
            s += av.x * cv.x + av.y * cv.y + av.z * cv.z + av.w * cv.w;
        }
        #pragma unroll
        for (int m2 = 1; m2 < 64; m2 <<= 1) s += __shfl_xor(s, m2, 64);
        if (lane == 0) diag[row] = s;
    }
}

// MX-scaled fp8 GEMM, 256x256 tile, 8 waves (2M x 4N), BK=128, dbuf LDS
// (128 KiB). Depth-1 async prefetch via global_load_lds; single barrier
// per K-step. Compute per K-step (~2200 cyc/SIMD of MFMA) now exceeds
// staging (~1200 cyc of L2 BW), so the vmcnt(0) drain at the barrier is
// mostly hidden. + exp + masked row-sum epilogue.
__global__ __launch_bounds__(512, 2) void gemm_expsum(
    const unsigned char* __restrict__ A0, const unsigned char* __restrict__ B0,
    float* __restrict__ S0,
    const unsigned char* __restrict__ A1, const unsigned char* __restrict__ B1,
    float* __restrict__ S1,
    const float* __restrict__ logit_scale, const int* __restrict__ offset,
    int Bn, int D)
{
    const int z = blockIdx.z;
    const unsigned char* A = z ? A1 : A0;
    const unsigned char* B = z ? B1 : B0;
    float* S = z ? S1 : S0;

    __shared__ unsigned char As[2][32768];   // 2 x (128-row tiles) fp8, dbuf
    __shared__ unsigned char Bs[2][32768];

    const int tid  = threadIdx.x;
    const int wave = tid >> 6;
    const int lane = tid & 63;
    const int lo   = lane & 15;
    const int qd   = lane >> 4;
    const int wm   = wave >> 2;              // 0..1  (M half)
    const int wn   = wave & 3;               // 0..3  (N quarter)
    const int offA = ((2 * qd) ^ (lo & 7)) * 16;   // first 16-B slot

    // XCD-bijective swizzle within each z-plane (nwg = 256, % 8 == 0):
    // XCD k gets 32 consecutive swz -> 2 full A-panel rows -> L2 reuse.
    const int nx  = gridDim.x;
    const int nwg = nx * gridDim.y;
    int wg = blockIdx.y * nx + blockIdx.x;
    int swz = ((nwg & 7) == 0) ? ((wg & 7) * (nwg >> 3) + (wg >> 3)) : wg;
    const int by = swz / nx;
    const int bx = swz - by * nx;

    const int kTiles = D >> 7;
    const unsigned char* Atile = A + (size_t)(2 * by) * kTiles * 16384;
    const unsigned char* Btile = B + (size_t)(2 * bx) * kTiles * 16384;

    // stage K-tile kb (A: rows 2*by..2*by+1, B: rows 2*bx..2*bx+1) -> buf
    auto stage = [&](int buf, int kb) {
        #pragma unroll
        for (int h = 0; h < 2; ++h) {
            const size_t tbase = (size_t)(h * kTiles + kb) * 16384;
            #pragma unroll
            for (int i = 0; i < 2; ++i) {
                const int u    = (i * 512 + tid) * 16;   // per-lane global
                const int loff = h * 16384 + i * 8192 + wave * 1024; // uniform
                __builtin_amdgcn_global_load_lds(
                    (const AS_GLOBAL unsigned int*)(Atile + tbase + u),
                    (AS_LDS unsigned int*)&As[buf][loff], 16, 0, 0);
                __builtin_amdgcn_global_load_lds(
                    (const AS_GLOBAL unsigned int*)(Btile + tbase + u),
                    (AS_LDS unsigned int*)&Bs[buf][loff], 16, 0, 0);
            }
        }
    };

    f32x4 acc[8][4];
    #pragma unroll
    for (int i = 0; i < 8; ++i)
        #pragma unroll
        for (int j = 0; j < 4; ++j)
            acc[i][j] = (f32x4){0.f, 0.f, 0.f, 0.f};

    // per-lane LDS fragment bases (r&7 == lo&7 for all ti/tj)
    const int aOff0 = wm * 16384 + lo * 128 + offA;                 // + ti*2048
    const int bOff0 = (wn >> 1) * 16384 + ((wn & 1) * 64 + lo) * 128 + offA;

    stage(0, 0);
    __syncthreads();          // drain prologue DMA

    for (int kb = 0; kb < kTiles; ++kb) {
        const int cur = kb & 1;
        if (kb + 1 < kTiles)
            stage(1 - cur, kb + 1);          // prefetch kb+1, in flight
                                             // under the whole MFMA phase
        i32x8 bq[4];
        #pragma unroll
        for (int tj = 0; tj < 4; ++tj) {
            const int ba = bOff0 + tj * 2048;
            union { int4 h[2]; i32x8 v; } u;
            u.h[0] = *(const int4*)&Bs[cur][ba];
            u.h[1] = *(const int4*)&Bs[cur][ba ^ 16];
            bq[tj] = u.v;
        }
        #pragma unroll
        for (int ti = 0; ti < 8; ++ti) {
            const int aa = aOff0 + ti * 2048;
            union { int4 h[2]; i32x8 v; } u;
            u.h[0] = *(const int4*)&As[cur][aa];
            u.h[1] = *(const int4*)&As[cur][aa ^ 16];
            i32x8 af = u.v;
            __builtin_amdgcn_s_setprio(1);
            #pragma unroll
            for (int tj = 0; tj < 4; ++tj)
                acc[ti][tj] = __builtin_amdgcn_mfma_scale_f32_16x16x128_f8f6f4(
                    af, bq[tj], acc[ti][tj],
                    0, 0,          // cbsz=fp8(e4m3), blgp=fp8(e4m3)
                    0, 127,        // scale A: opsel 0, E8M0 127 = x1.0
                    0, 127);       // scale B
            __builtin_amdgcn_s_setprio(0);
        }
        __syncthreads();   // all waves done with buf[cur]; drains kb+1 DMA
                           // that had the whole compute phase in flight
    }

    const float ls = logit_scale[0];
    const int offs = offset[0];
    const int rowBase = by * 256 + wm * 128;
    const int colBase = bx * 256 + wn * 64;
    #pragma unroll
    for (int ti = 0; ti < 8; ++ti) {
        #pragma unroll
        for (int r = 0; r < 4; ++r) {
            int gi = rowBase + 16 * ti + 4 * qd + r;     // C/D row=quad*4+reg
            float rs = 0.f;
            #pragma unroll
            for (int tj = 0; tj < 4; ++tj) {
                int gj = colBase + 16 * tj + lo;         // C/D col=lane&15
                float e = __expf(ls * acc[ti][tj][r]);
                if (gj == gi + offs) e = 0.f;            // shifted diagonal
                rs += e;
            }
            #pragma unroll
            for (int m = 1; m < 16; m <<= 1) rs += __shfl_xor(rs, m, 64);
            if (lo == 0) atomicAdd(&S[gi], rs);
        }
    }
}

// 8-block reduction; last block (ticket) computes the scalar loss.
__global__ __launch_bounds__(256) void final_kernel(
    const float* __restrict__ S_im, const float* __restrict__ S_tt,
    const float* __restrict__ diag,
    const float* __restrict__ ru_im, const float* __restrict__ ru_tt,
    const float* __restrict__ l1_im, const float* __restrict__ l1_tt,
    const float* __restrict__ u_im,  const float* __restrict__ u_tt,
    const float* __restrict__ logit_scale, float* __restrict__ red,
    float* __restrict__ out, int Bn)
{
    const float ls = logit_scale[0];
    const float inv_rw = 1.0f / (float)(Bn - 1);
    const int gid = blockIdx.x * 256 + threadIdx.x;
    float pg = 0.f, lg = 0.f;
    for (int i = gid; i < Bn; i += 8 * 256) {
        float p1 = l1_im[i] / (u_im[i] + EPSF) + l1_tt[i] / (u_tt[i] + EPSF);
        float dd = expf(-ls * diag[i]);
        float p2 = dd * S_im[i] * inv_rw / (ru_im[i] + EPSF)
                 + dd * S_tt[i] * inv_rw / (ru_tt[i] + EPSF);
        pg += p1 + p2;
        lg += logf(u_im[i]) + logf(u_tt[i]);
    }
    __shared__ float sp[256], sl[256];
    sp[threadIdx.x] = pg; sl[threadIdx.x] = lg;
    __syncthreads();
    for (int s = 128; s > 0; s >>= 1) {
        if (threadIdx.x < s) { sp[threadIdx.x] += sp[threadIdx.x + s];
                               sl[threadIdx.x] += sl[threadIdx.x + s]; }
        __syncthreads();
    }
    if (threadIdx.x == 0) {
        atomicAdd(&red[0], sp[0]);
        atomicAdd(&red[1], sl[0]);
        __threadfence();
        int t = atomicAdd((int*)&red[2], 1);
        if (t == gridDim.x - 1) {
            float pgSum = atomicAdd(&red[0], 0.f);
            float lgSum = atomicAdd(&red[1], 0.f);
            float loss = ((pgSum / (float)Bn) * 0.5f) / ls
                       + RHOF / ls
                       + (lgSum / (float)Bn) * 0.5f / ls;
            out[0] = loss;
        }
    }
}

extern "C" void kernel_launch(void* const* d_in, const int* in_sizes, int n_in,
                              void* d_out, int out_size, void* d_ws, size_t ws_size,
                              hipStream_t stream) {
    const float* im    = (const float*)d_in[0];
    const float* tt    = (const float*)d_in[1];
    const float* rim   = (const float*)d_in[2];
    const float* rtt   = (const float*)d_in[3];
    const float* ru_im = (const float*)d_in[4];
    const float* ru_tt = (const float*)d_in[5];
    const float* l1_im = (const float*)d_in[6];
    const float* l1_tt = (const float*)d_in[7];
    const float* u_im  = (const float*)d_in[8];
    const float* u_tt  = (const float*)d_in[9];
    const float* lsc   = (const float*)d_in[10];
    const int*   offs  = (const int*)d_in[11];

    const int Bn = in_sizes[4];          // 4096
    const int D  = in_sizes[0] / Bn;     // 1024
    const int spm = Bn / 8;              // 8-row slabs per matrix

    char* base = (char*)d_ws;
    float* S_im = (float*)base;
    float* S_tt = S_im + Bn;
    float* diag = S_tt + Bn;
    float* red  = diag + Bn;             // [0]=pg, [1]=lg, [2]=ticket
    const size_t headBytes = (((size_t)(3 * Bn + 8) * sizeof(float)) + 255) & ~(size_t)255;
    const size_t matBytes  = (size_t)Bn * D;          // fp8: 1 B/elem
    unsigned char* buf0 = (unsigned char*)(base + headBytes);
    unsigned char* bRim = buf0;
    unsigned char* bTt  = buf0 + matBytes;
    unsigned char* bRtt = buf0 + 2 * matBytes;
    unsigned char* bIm  = buf0 + 3 * matBytes;

    prep_fp8<<<4 * spm + Bn / 4, 256, 0, stream>>>(
        im, tt, rim, rtt, bIm, bTt, bRim, bRtt, S_im, S_tt, diag, red, D, spm);

    dim3 ggrid(Bn / 256, Bn / 256, 2);
    gemm_expsum<<<ggrid, 512, 0, stream>>>(bRim, bTt, S_im, bRtt, bIm, S_tt,
                                           lsc, offs, Bn, D);

    final_kernel<<<8, 256, 0, stream>>>(S_im, S_tt, diag, ru_im, ru_tt,
                                        l1_im, l1_tt, u_im, u_tt, lsc,
                                        red, (float*)d_out, Bn);
}

// Round 3
// 177.993 us; speedup vs baseline: 1.0363x; 1.0219x over previous
//
#include <hip/hip_runtime.h>
#include <hip/hip_bf16.h>

#define EPSF 1e-14f
#define RHOF 8.0f

typedef __attribute__((ext_vector_type(4))) float f32x4;
typedef __attribute__((ext_vector_type(8))) int   i32x8;
typedef __attribute__((ext_vector_type(2))) unsigned long long u64x2;

#define AS_GLOBAL __attribute__((address_space(1)))
#define AS_LDS    __attribute__((address_space(3)))

// fp8 packed layout, BK=128 (for mfma_scale 16x16x128). Tile = 128 rows x
// 128 cols fp8 = 16 KB = 1024 units of 16 B. Row r = 8 units; content unit
// u stored at slot u ^ (r&7). Fragment (quad qd) needs k-block qd*32..+31 =
// content units {2qd, 2qd+1} -> slots s0=(2qd)^(lo&7), s0^1: two
// ds_read_b128. Per 16-lane phase s0 covers 8 slots twice -> 32 banks
// 2-way (free, m136). global_load_lds deposit order == packed order.

__global__ __launch_bounds__(256) void prep_fp8(
    const float* __restrict__ im,  const float* __restrict__ tt,
    const float* __restrict__ rim, const float* __restrict__ rtt,
    unsigned char* __restrict__ bIm,  unsigned char* __restrict__ bTt,
    unsigned char* __restrict__ bRim, unsigned char* __restrict__ bRtt,
    float* __restrict__ S_im, float* __restrict__ S_tt,
    float* __restrict__ diag, float* __restrict__ red,
    int D, int spm /* 8-row slabs per matrix */)
{
    __shared__ unsigned char L[8 * 1024];   // 8 rows x D fp8 (D<=1024)
    const int b = blockIdx.x;
    const int tid = threadIdx.x;
    const int nConv = 4 * spm;
    if (b < nConv) {
        int mIdx = b / spm;
        int slab = b - mIdx * spm;
        const float* src = (mIdx == 0) ? rim : (mIdx == 1) ? tt
                          : (mIdx == 2) ? rtt : im;
        unsigned char* dst = (mIdx == 0) ? bRim : (mIdx == 1) ? bTt
                            : (mIdx == 2) ? bRtt : bIm;
        const float* srow = src + (size_t)slab * 8 * D;
        const int n4 = (8 * D) >> 2;
        for (int idx = tid; idx < n4; idx += 256) {
            float4 v = *(const float4*)(srow + idx * 4);
            int pk = __builtin_amdgcn_cvt_pk_fp8_f32(v.x, v.y, 0, false);
            pk     = __builtin_amdgcn_cvt_pk_fp8_f32(v.z, v.w, pk, true);
            *(int*)&L[idx * 4] = pk;
        }
        __syncthreads();
        const int kTiles = D >> 7;               // 128-wide k tiles
        const int rb = (slab * 8) >> 7;
        const int r0loc = (slab * 8) & 127;
        for (int g = tid; g < (D >> 1); g += 256) {  // units per slab = D/2
            int kb  = g >> 6;                    // 64 units per (slab,kb)
            int rem = g & 63;
            int rl  = rem >> 3;
            int p   = rem & 7;                   // slot position
            int r   = slab * 8 + rl;
            int c   = p ^ (r & 7);               // content unit at slot p
            const unsigned char* lb = &L[rl * D + kb * 128 + c * 16];
            u64x2 o = *(const u64x2*)lb;
            char* outp = (char*)dst
                       + ((size_t)(rb * kTiles + kb) * 1024
                          + (size_t)(r0loc + rl) * 8 + p) * 16;
            *(u64x2*)outp = o;
        }
    } else {
        int db = b - nConv;
        if (db == 0 && tid < 8) red[tid] = 0.f;
        if (tid < 4) { S_im[db * 4 + tid] = 0.f; S_tt[db * 4 + tid] = 0.f; }
        int row  = db * 4 + (tid >> 6);
        int lane = tid & 63;
        const float* a = rim + (size_t)row * D;
        const float* c = rtt + (size_t)row * D;
        float s = 0.f;
        for (int k = lane * 4; k < D; k += 256) {
            float4 av = *(const float4*)(a + k);
            float4 cv = *(const float4*)(c + k);
            s += av.x * cv.x + av.y * cv.y + av.z * cv.z + av.w * cv.w;
        }
        #pragma unroll
        for (int m2 = 1; m2 < 64; m2 <<= 1) s += __shfl_xor(s, m2, 64);
        if (lane == 0) diag[row] = s;
    }
}

// MX-scaled fp8 GEMM, 256x256 tile, 8 waves (2M x 4N), BK=128, dbuf LDS
// (128 KiB). 8-phase-style schedule (T3+T4): owner-staged DMA halves +
// 4 {ds_read -> s_barrier -> MFMA cluster -> s_barrier} phases per K-tile,
// raw barriers (no compiler vmcnt(0)-drain), one cheap per-wave vmcnt(0)
// on loads issued a full tile earlier. + exp + masked row-sum epilogue.
__global__ __launch_bounds__(512, 2) void gemm_expsum(
    const unsigned char* __restrict__ A0, const unsigned char* __restrict__ B0,
    float* __restrict__ S0,
    const unsigned char* __restrict__ A1, const unsigned char* __restrict__ B1,
    float* __restrict__ S1,
    const float* __restrict__ logit_scale, const int* __restrict__ offset,
    int Bn, int D)
{
    const int z = blockIdx.z;
    const unsigned char* A = z ? A1 : A0;
    const unsigned char* B = z ? B1 : B0;
    float* S = z ? S1 : S0;

    __shared__ unsigned char As[2][32768];   // 2 x (128-row halves), dbuf
    __shared__ unsigned char Bs[2][32768];

    const int tid  = threadIdx.x;
    const int wave = tid >> 6;
    const int lane = tid & 63;
    const int lo   = lane & 15;
    const int qd   = lane >> 4;
    const int wm   = wave >> 2;              // 0..1  (M half)
    const int wn   = wave & 3;               // 0..3  (N quarter)
    const int offA = ((2 * qd) ^ (lo & 7)) * 16;   // first 16-B slot

    // XCD-bijective swizzle within each z-plane (nwg = 256, % 8 == 0).
    const int nx  = gridDim.x;
    const int nwg = nx * gridDim.y;
    int wg = blockIdx.y * nx + blockIdx.x;
    int swz = ((nwg & 7) == 0) ? ((wg & 7) * (nwg >> 3) + (wg >> 3)) : wg;
    const int by = swz / nx;
    const int bx = swz - by * nx;

    const int kTiles = D >> 7;
    const unsigned char* Atile = A + (size_t)(2 * by) * kTiles * 16384;
    const unsigned char* Btile = B + (size_t)(2 * bx) * kTiles * 16384;

    // Owner staging: wave pair (wave>>1) owns one 16 KB half-tile
    // {A0,A1,B0,B1}; part = wave&1 stages 8 KB of it (8 x 16 B per lane).
    // Deposit is identity (linear) within the half, so LDS layout is
    // unchanged from the proven packed format.
    const int half = wave >> 1;              // 0:A-h0 1:A-h1 2:B-h0 3:B-h1
    const int part = wave & 1;
    const unsigned char* ownerG =
        (half < 2) ? Atile + (size_t)half * kTiles * 16384
                   : Btile + (size_t)(half - 2) * kTiles * 16384;
    const unsigned char* ownerGL = ownerG + part * 8192 + lane * 16; // /lane
    const int ownerLoff = (half & 1) * 16384 + part * 8192;          // unifrm
    const bool ownerIsA = (half < 2);

    auto stageOwner = [&](int buf, int kb) {
        const unsigned char* g = ownerGL + (size_t)kb * 16384;
        unsigned char* l = (ownerIsA ? &As[buf][0] : &Bs[buf][0]) + ownerLoff;
        #pragma unroll
        for (int q = 0; q < 8; ++q)
            __builtin_amdgcn_global_load_lds(
                (const AS_GLOBAL unsigned int*)(g + q * 1024),
                (AS_LDS unsigned int*)(l + q * 1024), 16, 0, 0);
    };

    f32x4 acc[8][4];
    #pragma unroll
    for (int i = 0; i < 8; ++i)
        #pragma unroll
        for (int j = 0; j < 4; ++j)
            acc[i][j] = (f32x4){0.f, 0.f, 0.f, 0.f};

    // per-lane LDS fragment bases (r&7 == lo&7 for all ti/tj)
    const int aOff0 = wm * 16384 + lo * 128 + offA;                 // + ti*2048
    const int bOff0 = (wn >> 1) * 16384 + ((wn & 1) * 64 + lo) * 128 + offA;

    stageOwner(0, 0);
    asm volatile("s_waitcnt vmcnt(0)" ::: "memory");
    __builtin_amdgcn_s_barrier();

    for (int kb = 0; kb < kTiles; ++kb) {
        const int cur = kb & 1;
        if (kb + 1 < kTiles)
            stageOwner(1 - cur, kb + 1);   // in flight across all 4 phases

        i32x8 bq[4];
        #pragma unroll
        for (int tj = 0; tj < 4; ++tj) {
            const int ba = bOff0 + tj * 2048;
            union { int4 h[2]; i32x8 v; } u;
            u.h[0] = *(const int4*)&Bs[cur][ba];
            u.h[1] = *(const int4*)&Bs[cur][ba ^ 16];
            bq[tj] = u.v;
        }

        #pragma unroll
        for (int ph = 0; ph < 4; ++ph) {
            // ds-load region of the phase: two A-frags (ti = 2ph, 2ph+1)
            const int ti0 = 2 * ph;
            union { int4 h[2]; i32x8 v; } ua0, ua1;
            {
                const int aa0 = aOff0 + ti0 * 2048;
                ua0.h[0] = *(const int4*)&As[cur][aa0];
                ua0.h[1] = *(const int4*)&As[cur][aa0 ^ 16];
                const int aa1 = aOff0 + (ti0 + 1) * 2048;
                ua1.h[0] = *(const int4*)&As[cur][aa1];
                ua1.h[1] = *(const int4*)&As[cur][aa1 ^ 16];
            }
            __builtin_amdgcn_s_barrier();          // phase-align waves
            __builtin_amdgcn_s_setprio(1);
            #pragma unroll
            for (int tj = 0; tj < 4; ++tj)
                acc[ti0][tj] = __builtin_amdgcn_mfma_scale_f32_16x16x128_f8f6f4(
                    ua0.v, bq[tj], acc[ti0][tj],
                    0, 0, 0, 127, 0, 127);
            #pragma unroll
            for (int tj = 0; tj < 4; ++tj)
                acc[ti0 + 1][tj] = __builtin_amdgcn_mfma_scale_f32_16x16x128_f8f6f4(
                    ua1.v, bq[tj], acc[ti0 + 1][tj],
                    0, 0, 0, 127, 0, 127);
            __builtin_amdgcn_s_setprio(0);
            __builtin_amdgcn_s_barrier();          // phase end
        }

        if (kb + 1 < kTiles) {
            // My 8 DMA loads for tile kb+1 were issued ~4 phases ago;
            // vmcnt(0)-own + barrier => all waves' deposits complete.
            asm volatile("s_waitcnt vmcnt(0)" ::: "memory");
            __builtin_amdgcn_s_barrier();
        }
    }

    const float ls = logit_scale[0];
    const int offs = offset[0];
    const int rowBase = by * 256 + wm * 128;
    const int colBase = bx * 256 + wn * 64;
    #pragma unroll
    for (int ti = 0; ti < 8; ++ti) {
        #pragma unroll
        for (int r = 0; r < 4; ++r) {
            int gi = rowBase + 16 * ti + 4 * qd + r;     // C/D row=quad*4+reg
            float rs = 0.f;
            #pragma unroll
            for (int tj = 0; tj < 4; ++tj) {
                int gj = colBase + 16 * tj + lo;         // C/D col=lane&15
                float e = __expf(ls * acc[ti][tj][r]);
                if (gj == gi + offs) e = 0.f;            // shifted diagonal
                rs += e;
            }
            #pragma unroll
            for (int m = 1; m < 16; m <<= 1) rs += __shfl_xor(rs, m, 64);
            if (lo == 0) atomicAdd(&S[gi], rs);
        }
    }
}

// 8-block reduction; last block (ticket) computes the scalar loss.
__global__ __launch_bounds__(256) void final_kernel(
    const float* __restrict__ S_im, const float* __restrict__ S_tt,
    const float* __restrict__ diag,
    const float* __restrict__ ru_im, const float* __restrict__ ru_tt,
    const float* __restrict__ l1_im, const float* __restrict__ l1_tt,
    const float* __restrict__ u_im,  const float* __restrict__ u_tt,
    const float* __restrict__ logit_scale, float* __restrict__ red,
    float* __restrict__ out, int Bn)
{
    const float ls = logit_scale[0];
    const float inv_rw = 1.0f / (float)(Bn - 1);
    const int gid = blockIdx.x * 256 + threadIdx.x;
    float pg = 0.f, lg = 0.f;
    for (int i = gid; i < Bn; i += 8 * 256) {
        float p1 = l1_im[i] / (u_im[i] + EPSF) + l1_tt[i] / (u_tt[i] + EPSF);
        float dd = expf(-ls * diag[i]);
        float p2 = dd * S_im[i] * inv_rw / (ru_im[i] + EPSF)
                 + dd * S_tt[i] * inv_rw / (ru_tt[i] + EPSF);
        pg += p1 + p2;
        lg += logf(u_im[i]) + logf(u_tt[i]);
    }
    __shared__ float sp[256], sl[256];
    sp[threadIdx.x] = pg; sl[threadIdx.x] = lg;
    __syncthreads();
    for (int s = 128; s > 0; s >>= 1) {
        if (threadIdx.x < s) { sp[threadIdx.x] += sp[threadIdx.x + s];
                               sl[threadIdx.x] += sl[threadIdx.x + s]; }
        __syncthreads();
    }
    if (threadIdx.x == 0) {
        atomicAdd(&red[0], sp[0]);
        atomicAdd(&red[1], sl[0]);
        __threadfence();
        int t = atomicAdd((int*)&red[2], 1);
        if (t == gridDim.x - 1) {
            float pgSum = atomicAdd(&red[0], 0.f);
            float lgSum = atomicAdd(&red[1], 0.f);
            float loss = ((pgSum / (float)Bn) * 0.5f) / ls
                       + RHOF / ls
                       + (lgSum / (float)Bn) * 0.5f / ls;
            out[0] = loss;
        }
    }
}

extern "C" void kernel_launch(void* const* d_in, const int* in_sizes, int n_in,
                              void* d_out, int out_size, void* d_ws, size_t ws_size,
                              hipStream_t stream) {
    const float* im    = (const float*)d_in[0];
    const float* tt    = (const float*)d_in[1];
    const float* rim   = (const float*)d_in[2];
    const float* rtt   = (const float*)d_in[3];
    const float* ru_im = (const float*)d_in[4];
    const float* ru_tt = (const float*)d_in[5];
    const float* l1_im = (const float*)d_in[6];
    const float* l1_tt = (const float*)d_in[7];
    const float* u_im  = (const float*)d_in[8];
    const float* u_tt  = (const float*)d_in[9];
    const float* lsc   = (const float*)d_in[10];
    const int*   offs  = (const int*)d_in[11];

    const int Bn = in_sizes[4];          // 4096
    const int D  = in_sizes[0] / Bn;     // 1024
    const int spm = Bn / 8;              // 8-row slabs per matrix

    char* base = (char*)d_ws;
    float* S_im = (float*)base;
    float* S_tt = S_im + Bn;
    float* diag = S_tt + Bn;
    float* red  = diag + Bn;             // [0]=pg, [1]=lg, [2]=ticket
    const size_t headBytes = (((size_t)(3 * Bn + 8) * sizeof(float)) + 255) & ~(size_t)255;
    const size_t matBytes  = (size_t)Bn * D;          // fp8: 1 B/elem
    unsigned char* buf0 = (unsigned char*)(base + headBytes);
    unsigned char* bRim = buf0;
    unsigned char* bTt  = buf0 + matBytes;
    unsigned char* bRtt = buf0 + 2 * matBytes;
    unsigned char* bIm  = buf0 + 3 * matBytes;

    prep_fp8<<<4 * spm + Bn / 4, 256, 0, stream>>>(
        im, tt, rim, rtt, bIm, bTt, bRim, bRtt, S_im, S_tt, diag, red, D, spm);

    dim3 ggrid(Bn / 256, Bn / 256, 2);
    gemm_expsum<<<ggrid, 512, 0, stream>>>(bRim, bTt, S_im, bRtt, bIm, S_tt,
                                           lsc, offs, Bn, D);

    final_kernel<<<8, 256, 0, stream>>>(S_im, S_tt, diag, ru_im, ru_tt,
                                        l1_im, l1_tt, u_im, u_tt, lsc,
                                        red, (float*)d_out, Bn);
}

// Round 4
// 176.943 us; speedup vs baseline: 1.0424x; 1.0059x over previous
//
#include <hip/hip_runtime.h>
#include <hip/hip_bf16.h>

#define EPSF 1e-14f
#define RHOF 8.0f

typedef __attribute__((ext_vector_type(4))) float f32x4;
typedef __attribute__((ext_vector_type(8))) int   i32x8;

#define AS_GLOBAL __attribute__((address_space(1)))
#define AS_LDS    __attribute__((address_space(3)))

// fp8 packed layout, BK=128 (for mfma_scale 16x16x128). Tile = 128 rows x
// 128 cols fp8 = 16 KB = 1024 units of 16 B. Row r = 8 units; content unit
// u stored at slot u ^ (r&7). Fragment (quad qd) needs k-block qd*32..+31 =
// content units {2qd, 2qd+1} -> slots s0=(2qd)^(lo&7), s0^1: two
// ds_read_b128. global_load_lds deposit order == packed order.

// One-pass prep: thread reads 16 contiguous fp32 (64 B), cvt_pk to 16 fp8,
// one 16-B store to the packed slot address. No LDS, no barrier.
__global__ __launch_bounds__(256) void prep_fp8(
    const float* __restrict__ im,  const float* __restrict__ tt,
    const float* __restrict__ rim, const float* __restrict__ rtt,
    unsigned char* __restrict__ bIm,  unsigned char* __restrict__ bTt,
    unsigned char* __restrict__ bRim, unsigned char* __restrict__ bRtt,
    float* __restrict__ S_im, float* __restrict__ S_tt,
    float* __restrict__ diag, float* __restrict__ red,
    int D, int bpm /* conversion blocks per matrix */)
{
    const int b = blockIdx.x;
    const int tid = threadIdx.x;
    const int nConv = 4 * bpm;
    if (b < nConv) {
        int mIdx = b / bpm;
        int blk  = b - mIdx * bpm;
        const float* src = (mIdx == 0) ? rim : (mIdx == 1) ? tt
                          : (mIdx == 2) ? rtt : im;
        unsigned char* dst = (mIdx == 0) ? bRim : (mIdx == 1) ? bTt
                            : (mIdx == 2) ? bRtt : bIm;
        const int upr = D >> 4;            // 16-B content units per row
        const int rpb = 256 / upr;         // rows per block (D=1024 -> 4)
        const int urow = tid / upr;
        const int c    = tid - urow * upr; // content unit within row
        const int r    = blk * rpb + urow;
        const int kTiles = D >> 7;
        const float* p = src + (size_t)r * D + (size_t)c * 16;
        float4 v0 = ((const float4*)p)[0];
        float4 v1 = ((const float4*)p)[1];
        float4 v2 = ((const float4*)p)[2];
        float4 v3 = ((const float4*)p)[3];
        int w0 = __builtin_amdgcn_cvt_pk_fp8_f32(v0.x, v0.y, 0, false);
        w0     = __builtin_amdgcn_cvt_pk_fp8_f32(v0.z, v0.w, w0, true);
        int w1 = __builtin_amdgcn_cvt_pk_fp8_f32(v1.x, v1.y, 0, false);
        w1     = __builtin_amdgcn_cvt_pk_fp8_f32(v1.z, v1.w, w1, true);
        int w2 = __builtin_amdgcn_cvt_pk_fp8_f32(v2.x, v2.y, 0, false);
        w2     = __builtin_amdgcn_cvt_pk_fp8_f32(v2.z, v2.w, w2, true);
        int w3 = __builtin_amdgcn_cvt_pk_fp8_f32(v3.x, v3.y, 0, false);
        w3     = __builtin_amdgcn_cvt_pk_fp8_f32(v3.z, v3.w, w3, true);
        int4 out = make_int4(w0, w1, w2, w3);
        const int kb = c >> 3;
        const int p8 = (c & 7) ^ (r & 7);          // XOR slot
        *(int4*)(dst + ((size_t)((r >> 7) * kTiles + kb) * 1024
                        + (size_t)(r & 127) * 8 + p8) * 16) = out;
    } else {
        int db = b - nConv;
        if (db == 0 && tid < 8) red[tid] = 0.f;
        if (tid < 4) { S_im[db * 4 + tid] = 0.f; S_tt[db * 4 + tid] = 0.f; }
        int row  = db * 4 + (tid >> 6);
        int lane = tid & 63;
        const float* a = rim + (size_t)row * D;
        const float* c2 = rtt + (size_t)row * D;
        float s = 0.f;
        for (int k = lane * 4; k < D; k += 256) {
            float4 av = *(const float4*)(a + k);
            float4 cv = *(const float4*)(c2 + k);
            s += av.x * cv.x + av.y * cv.y + av.z * cv.z + av.w * cv.w;
        }
        #pragma unroll
        for (int m2 = 1; m2 < 64; m2 <<= 1) s += __shfl_xor(s, m2, 64);
        if (lane == 0) diag[row] = s;
    }
}

// MX-scaled fp8 GEMM, 256x256 tile, 8 waves (2M x 4N), BK=128, dbuf LDS.
// z-merged: 256 fat blocks (1/CU exactly), each computing the z=0 tile
// then the z=1 tile; z1's tile-0 DMA issues during z0's last K-tile and
// drains under z0's epilogue. Requires kTiles even (buffer parity).
// K-loop body: 4 {ds_read -> s_barrier -> MFMA cluster -> s_barrier}
// phases per K-tile, raw barriers, per-wave vmcnt(0) on own DMA only.
__global__ __launch_bounds__(512, 2) void gemm_expsum(
    const unsigned char* __restrict__ A0, const unsigned char* __restrict__ B0,
    float* __restrict__ S0,
    const unsigned char* __restrict__ A1, const unsigned char* __restrict__ B1,
    float* __restrict__ S1,
    const float* __restrict__ logit_scale, const int* __restrict__ offset,
    int Bn, int D)
{
    __shared__ unsigned char As[2][32768];   // 2 x (128-row halves), dbuf
    __shared__ unsigned char Bs[2][32768];

    const int tid  = threadIdx.x;
    const int wave = tid >> 6;
    const int lane = tid & 63;
    const int lo   = lane & 15;
    const int qd   = lane >> 4;
    const int wm   = wave >> 2;              // 0..1  (M half)
    const int wn   = wave & 3;               // 0..3  (N quarter)
    const int offA = ((2 * qd) ^ (lo & 7)) * 16;   // first 16-B slot

    // XCD-bijective swizzle (nwg = 256, % 8 == 0).
    const int nx  = gridDim.x;
    const int nwg = nx * gridDim.y;
    int wg = blockIdx.y * nx + blockIdx.x;
    int swz = ((nwg & 7) == 0) ? ((wg & 7) * (nwg >> 3) + (wg >> 3)) : wg;
    const int by = swz / nx;
    const int bx = swz - by * nx;

    const int kTiles = D >> 7;

    // Owner staging: wave pair (wave>>1) owns one 16 KB half-tile
    // {A-h0,A-h1,B-h0,B-h1}; part = wave&1 stages 8 KB (8 x 16 B / lane).
    const int half = wave >> 1;
    const int part = wave & 1;
    const bool ownerIsA = (half < 2);
    const int ownerLoff = (half & 1) * 16384 + part * 8192;

    auto stageOwner = [&](int buf, const unsigned char* At,
                          const unsigned char* Bt, int kb) {
        const unsigned char* g =
            (ownerIsA ? At + (size_t)half * kTiles * 16384
                      : Bt + (size_t)(half - 2) * kTiles * 16384)
            + (size_t)kb * 16384 + part * 8192 + lane * 16;
        unsigned char* l = (ownerIsA ? &As[buf][0] : &Bs[buf][0]) + ownerLoff;
        #pragma unroll
        for (int q = 0; q < 8; ++q)
            __builtin_amdgcn_global_load_lds(
                (const AS_GLOBAL unsigned int*)(g + q * 1024),
                (AS_LDS unsigned int*)(l + q * 1024), 16, 0, 0);
    };

    // per-lane LDS fragment bases (r&7 == lo&7 for all ti/tj)
    const int aOff0 = wm * 16384 + lo * 128 + offA;                 // + ti*2048
    const int bOff0 = (wn >> 1) * 16384 + ((wn & 1) * 64 + lo) * 128 + offA;

    const float ls = logit_scale[0];
    const int offs = offset[0];

    for (int zz = 0; zz < 2; ++zz) {
        const unsigned char* A = zz ? A1 : A0;
        const unsigned char* B = zz ? B1 : B0;
        float* S = zz ? S1 : S0;
        const unsigned char* Atile = A + (size_t)(2 * by) * kTiles * 16384;
        const unsigned char* Btile = B + (size_t)(2 * bx) * kTiles * 16384;

        f32x4 acc[8][4];
        #pragma unroll
        for (int i = 0; i < 8; ++i)
            #pragma unroll
            for (int j = 0; j < 4; ++j)
                acc[i][j] = (f32x4){0.f, 0.f, 0.f, 0.f};

        if (zz == 0) {                       // cold prologue (z0 only)
            stageOwner(0, Atile, Btile, 0);
            asm volatile("s_waitcnt vmcnt(0)" ::: "memory");
            __builtin_amdgcn_s_barrier();
        }
        // zz==1: tile0 was staged at z0's last K-tile and drained under
        // z0's epilogue; sits in buf0 (kTiles even -> parity matches).

        for (int kb = 0; kb < kTiles; ++kb) {
            const int cur = kb & 1;
            if (kb + 1 < kTiles) {
                stageOwner(1 - cur, Atile, Btile, kb + 1);
            } else if (zz == 0) {            // last tile of z0: stage z1 t0
                stageOwner(1 - cur,
                           A1 + (size_t)(2 * by) * kTiles * 16384,
                           B1 + (size_t)(2 * bx) * kTiles * 16384, 0);
            }

            i32x8 bq[4];
            #pragma unroll
            for (int tj = 0; tj < 4; ++tj) {
                const int ba = bOff0 + tj * 2048;
                union { int4 h[2]; i32x8 v; } u;
                u.h[0] = *(const int4*)&Bs[cur][ba];
                u.h[1] = *(const int4*)&Bs[cur][ba ^ 16];
                bq[tj] = u.v;
            }

            #pragma unroll
            for (int ph = 0; ph < 4; ++ph) {
                const int ti0 = 2 * ph;
                union { int4 h[2]; i32x8 v; } ua0, ua1;
                {
                    const int aa0 = aOff0 + ti0 * 2048;
                    ua0.h[0] = *(const int4*)&As[cur][aa0];
                    ua0.h[1] = *(const int4*)&As[cur][aa0 ^ 16];
                    const int aa1 = aOff0 + (ti0 + 1) * 2048;
                    ua1.h[0] = *(const int4*)&As[cur][aa1];
                    ua1.h[1] = *(const int4*)&As[cur][aa1 ^ 16];
                }
                __builtin_amdgcn_s_barrier();          // phase-align
                __builtin_amdgcn_s_setprio(1);
                #pragma unroll
                for (int tj = 0; tj < 4; ++tj)
                    acc[ti0][tj] = __builtin_amdgcn_mfma_scale_f32_16x16x128_f8f6f4(
                        ua0.v, bq[tj], acc[ti0][tj],
                        0, 0, 0, 127, 0, 127);
                #pragma unroll
                for (int tj = 0; tj < 4; ++tj)
                    acc[ti0 + 1][tj] = __builtin_amdgcn_mfma_scale_f32_16x16x128_f8f6f4(
                        ua1.v, bq[tj], acc[ti0 + 1][tj],
                        0, 0, 0, 127, 0, 127);
                __builtin_amdgcn_s_setprio(0);
                __builtin_amdgcn_s_barrier();          // phase end
            }

            if (kb + 1 < kTiles) {
                // own DMA for kb+1 issued ~4 phases ago: cheap drain
                asm volatile("s_waitcnt vmcnt(0)" ::: "memory");
                __builtin_amdgcn_s_barrier();
            }
        }

        // epilogue for this z; z1's tile-0 DMA (if zz==0) flies under it
        const int rowBase = by * 256 + wm * 128;
        const int colBase = bx * 256 + wn * 64;
        #pragma unroll
        for (int ti = 0; ti < 8; ++ti) {
            #pragma unroll
            for (int r = 0; r < 4; ++r) {
                int gi = rowBase + 16 * ti + 4 * qd + r; // C/D row=quad*4+reg
                float rs = 0.f;
                #pragma unroll
                for (int tj = 0; tj < 4; ++tj) {
                    int gj = colBase + 16 * tj + lo;     // C/D col=lane&15
                    float e = __expf(ls * acc[ti][tj][r]);
                    if (gj == gi + offs) e = 0.f;        // shifted diagonal
                    rs += e;
                }
                #pragma unroll
                for (int m = 1; m < 16; m <<= 1) rs += __shfl_xor(rs, m, 64);
                if (lo == 0) atomicAdd(&S[gi], rs);
            }
        }

        if (zz == 0) {                       // drain z1 tile0 before z1 loop
            asm volatile("s_waitcnt vmcnt(0)" ::: "memory");
            __builtin_amdgcn_s_barrier();
        }
    }
}

// 32-block reduction; last block (ticket) computes the scalar loss.
__global__ __launch_bounds__(256) void final_kernel(
    const float* __restrict__ S_im, const float* __restrict__ S_tt,
    const float* __restrict__ diag,
    const float* __restrict__ ru_im, const float* __restrict__ ru_tt,
    const float* __restrict__ l1_im, const float* __restrict__ l1_tt,
    const float* __restrict__ u_im,  const float* __restrict__ u_tt,
    const float* __restrict__ logit_scale, float* __restrict__ red,
    float* __restrict__ out, int Bn)
{
    const float ls = logit_scale[0];
    const float inv_rw = 1.0f / (float)(Bn - 1);
    const int gid = blockIdx.x * 256 + threadIdx.x;
    const int stride = gridDim.x * 256;
    float pg = 0.f, lg = 0.f;
    for (int i = gid; i < Bn; i += stride) {
        float p1 = l1_im[i] / (u_im[i] + EPSF) + l1_tt[i] / (u_tt[i] + EPSF);
        float dd = expf(-ls * diag[i]);
        float p2 = dd * S_im[i] * inv_rw / (ru_im[i] + EPSF)
                 + dd * S_tt[i] * inv_rw / (ru_tt[i] + EPSF);
        pg += p1 + p2;
        lg += logf(u_im[i]) + logf(u_tt[i]);
    }
    __shared__ float sp[256], sl[256];
    sp[threadIdx.x] = pg; sl[threadIdx.x] = lg;
    __syncthreads();
    for (int s = 128; s > 0; s >>= 1) {
        if (threadIdx.x < s) { sp[threadIdx.x] += sp[threadIdx.x + s];
                               sl[threadIdx.x] += sl[threadIdx.x + s]; }
        __syncthreads();
    }
    if (threadIdx.x == 0) {
        atomicAdd(&red[0], sp[0]);
        atomicAdd(&red[1], sl[0]);
        __threadfence();
        int t = atomicAdd((int*)&red[2], 1);
        if (t == gridDim.x - 1) {
            float pgSum = atomicAdd(&red[0], 0.f);
            float lgSum = atomicAdd(&red[1], 0.f);
            float loss = ((pgSum / (float)Bn) * 0.5f) / ls
                       + RHOF / ls
                       + (lgSum / (float)Bn) * 0.5f / ls;
            out[0] = loss;
        }
    }
}

extern "C" void kernel_launch(void* const* d_in, const int* in_sizes, int n_in,
                              void* d_out, int out_size, void* d_ws, size_t ws_size,
                              hipStream_t stream) {
    const float* im    = (const float*)d_in[0];
    const float* tt    = (const float*)d_in[1];
    const float* rim   = (const float*)d_in[2];
    const float* rtt   = (const float*)d_in[3];
    const float* ru_im = (const float*)d_in[4];
    const float* ru_tt = (const float*)d_in[5];
    const float* l1_im = (const float*)d_in[6];
    const float* l1_tt = (const float*)d_in[7];
    const float* u_im  = (const float*)d_in[8];
    const float* u_tt  = (const float*)d_in[9];
    const float* lsc   = (const float*)d_in[10];
    const int*   offs  = (const int*)d_in[11];

    const int Bn = in_sizes[4];          // 4096
    const int D  = in_sizes[0] / Bn;     // 1024
    const int rpb = 4096 / D;            // rows per conversion block
    const int bpm = Bn / rpb;            // conversion blocks per matrix

    char* base = (char*)d_ws;
    float* S_im = (float*)base;
    float* S_tt = S_im + Bn;
    float* diag = S_tt + Bn;
    float* red  = diag + Bn;             // [0]=pg, [1]=lg, [2]=ticket
    const size_t headBytes = (((size_t)(3 * Bn + 8) * sizeof(float)) + 255) & ~(size_t)255;
    const size_t matBytes  = (size_t)Bn * D;          // fp8: 1 B/elem
    unsigned char* buf0 = (unsigned char*)(base + headBytes);
    unsigned char* bRim = buf0;
    unsigned char* bTt  = buf0 + matBytes;
    unsigned char* bRtt = buf0 + 2 * matBytes;
    unsigned char* bIm  = buf0 + 3 * matBytes;

    prep_fp8<<<4 * bpm + Bn / 4, 256, 0, stream>>>(
        im, tt, rim, rtt, bIm, bTt, bRim, bRtt, S_im, S_tt, diag, red, D, bpm);

    dim3 ggrid(Bn / 256, Bn / 256, 1);
    gemm_expsum<<<ggrid, 512, 0, stream>>>(bRim, bTt, S_im, bRtt, bIm, S_tt,
                                           lsc, offs, Bn, D);

    final_kernel<<<32, 256, 0, stream>>>(S_im, S_tt, diag, ru_im, ru_tt,
                                         l1_im, l1_tt, u_im, u_tt, lsc,
                                         red, (float*)d_out, Bn);
}

// Round 5
// 174.295 us; speedup vs baseline: 1.0583x; 1.0152x over previous
//
#include <hip/hip_runtime.h>
#include <hip/hip_bf16.h>

#define EPSF 1e-14f
#define RHOF 8.0f

typedef __attribute__((ext_vector_type(4))) float f32x4;
typedef __attribute__((ext_vector_type(8))) int   i32x8;

#define AS_GLOBAL __attribute__((address_space(1)))
#define AS_LDS    __attribute__((address_space(3)))

// fp8 packed layout, BK=128 (for mfma_scale 16x16x128). Tile = 128 rows x
// 128 cols fp8 = 16 KB = 1024 units of 16 B. Row r = 8 units; content unit
// u stored at slot u ^ (r&7). Fragment (quad qd) needs k-block qd*32..+31 =
// content units {2qd, 2qd+1} -> slots s0=(2qd)^(lo&7), s0^1: two
// ds_read_b128. global_load_lds deposit order == packed order.

// One-pass prep: thread reads 16 contiguous fp32 (64 B), cvt_pk to 16 fp8,
// one 16-B store to the packed slot address. No LDS, no barrier.
__global__ __launch_bounds__(256) void prep_fp8(
    const float* __restrict__ im,  const float* __restrict__ tt,
    const float* __restrict__ rim, const float* __restrict__ rtt,
    unsigned char* __restrict__ bIm,  unsigned char* __restrict__ bTt,
    unsigned char* __restrict__ bRim, unsigned char* __restrict__ bRtt,
    float* __restrict__ S_im, float* __restrict__ S_tt,
    float* __restrict__ diag, float* __restrict__ red,
    int D, int bpm /* conversion blocks per matrix */)
{
    const int b = blockIdx.x;
    const int tid = threadIdx.x;
    const int nConv = 4 * bpm;
    if (b < nConv) {
        int mIdx = b / bpm;
        int blk  = b - mIdx * bpm;
        const float* src = (mIdx == 0) ? rim : (mIdx == 1) ? tt
                          : (mIdx == 2) ? rtt : im;
        unsigned char* dst = (mIdx == 0) ? bRim : (mIdx == 1) ? bTt
                            : (mIdx == 2) ? bRtt : bIm;
        const int upr = D >> 4;            // 16-B content units per row
        const int rpb = 256 / upr;         // rows per block (D=1024 -> 4)
        const int urow = tid / upr;
        const int c    = tid - urow * upr; // content unit within row
        const int r    = blk * rpb + urow;
        const int kTiles = D >> 7;
        const float* p = src + (size_t)r * D + (size_t)c * 16;
        float4 v0 = ((const float4*)p)[0];
        float4 v1 = ((const float4*)p)[1];
        float4 v2 = ((const float4*)p)[2];
        float4 v3 = ((const float4*)p)[3];
        int w0 = __builtin_amdgcn_cvt_pk_fp8_f32(v0.x, v0.y, 0, false);
        w0     = __builtin_amdgcn_cvt_pk_fp8_f32(v0.z, v0.w, w0, true);
        int w1 = __builtin_amdgcn_cvt_pk_fp8_f32(v1.x, v1.y, 0, false);
        w1     = __builtin_amdgcn_cvt_pk_fp8_f32(v1.z, v1.w, w1, true);
        int w2 = __builtin_amdgcn_cvt_pk_fp8_f32(v2.x, v2.y, 0, false);
        w2     = __builtin_amdgcn_cvt_pk_fp8_f32(v2.z, v2.w, w2, true);
        int w3 = __builtin_amdgcn_cvt_pk_fp8_f32(v3.x, v3.y, 0, false);
        w3     = __builtin_amdgcn_cvt_pk_fp8_f32(v3.z, v3.w, w3, true);
        int4 out = make_int4(w0, w1, w2, w3);
        const int kb = c >> 3;
        const int p8 = (c & 7) ^ (r & 7);          // XOR slot
        *(int4*)(dst + ((size_t)((r >> 7) * kTiles + kb) * 1024
                        + (size_t)(r & 127) * 8 + p8) * 16) = out;
    } else {
        int db = b - nConv;
        if (db == 0 && tid < 8) red[tid] = 0.f;
        if (tid < 4) { S_im[db * 4 + tid] = 0.f; S_tt[db * 4 + tid] = 0.f; }
        int row  = db * 4 + (tid >> 6);
        int lane = tid & 63;
        const float* a = rim + (size_t)row * D;
        const float* c2 = rtt + (size_t)row * D;
        float s = 0.f;
        for (int k = lane * 4; k < D; k += 256) {
            float4 av = *(const float4*)(a + k);
            float4 cv = *(const float4*)(c2 + k);
            s += av.x * cv.x + av.y * cv.y + av.z * cv.z + av.w * cv.w;
        }
        #pragma unroll
        for (int m2 = 1; m2 < 64; m2 <<= 1) s += __shfl_xor(s, m2, 64);
        if (lane == 0) diag[row] = s;
    }
}

// MX-scaled fp8 GEMM, 256x256 tile, 8 waves (2M x 4N), BK=128, dbuf LDS.
// z-merged: 256 fat blocks (1/CU), each computing the z=0 tile then the
// z=1 tile; z1's tile-0 DMA issues during z0's last K-tile and drains
// under z0's epilogue. NO intra-tile barriers: ds_read and MFMA are one
// compiler-scheduled region (m97 implicit-overlap regime) so LDS reads of
// one wave hide under MFMAs of another. Tile boundary: per-wave vmcnt(0)
// on OWN DMA (issued a full tile earlier -> cheap) + raw s_barrier.
__global__ __launch_bounds__(512, 2) void gemm_expsum(
    const unsigned char* __restrict__ A0, const unsigned char* __restrict__ B0,
    float* __restrict__ S0,
    const unsigned char* __restrict__ A1, const unsigned char* __restrict__ B1,
    float* __restrict__ S1,
    const float* __restrict__ logit_scale, const int* __restrict__ offset,
    int Bn, int D)
{
    __shared__ unsigned char As[2][32768];   // 2 x (128-row halves), dbuf
    __shared__ unsigned char Bs[2][32768];

    const int tid  = threadIdx.x;
    const int wave = tid >> 6;
    const int lane = tid & 63;
    const int lo   = lane & 15;
    const int qd   = lane >> 4;
    const int wm   = wave >> 2;              // 0..1  (M half)
    const int wn   = wave & 3;               // 0..3  (N quarter)
    const int offA = ((2 * qd) ^ (lo & 7)) * 16;   // first 16-B slot

    // XCD-bijective swizzle (nwg = 256, % 8 == 0).
    const int nx  = gridDim.x;
    const int nwg = nx * gridDim.y;
    int wg = blockIdx.y * nx + blockIdx.x;
    int swz = ((nwg & 7) == 0) ? ((wg & 7) * (nwg >> 3) + (wg >> 3)) : wg;
    const int by = swz / nx;
    const int bx = swz - by * nx;

    const int kTiles = D >> 7;

    // Owner staging: wave pair (wave>>1) owns one 16 KB half-tile
    // {A-h0,A-h1,B-h0,B-h1}; part = wave&1 stages 8 KB (8 x 16 B / lane).
    const int half = wave >> 1;
    const int part = wave & 1;
    const bool ownerIsA = (half < 2);
    const int ownerLoff = (half & 1) * 16384 + part * 8192;

    auto stageOwner = [&](int buf, const unsigned char* At,
                          const unsigned char* Bt, int kb) {
        const unsigned char* g =
            (ownerIsA ? At + (size_t)half * kTiles * 16384
                      : Bt + (size_t)(half - 2) * kTiles * 16384)
            + (size_t)kb * 16384 + part * 8192 + lane * 16;
        unsigned char* l = (ownerIsA ? &As[buf][0] : &Bs[buf][0]) + ownerLoff;
        #pragma unroll
        for (int q = 0; q < 8; ++q)
            __builtin_amdgcn_global_load_lds(
                (const AS_GLOBAL unsigned int*)(g + q * 1024),
                (AS_LDS unsigned int*)(l + q * 1024), 16, 0, 0);
    };

    // per-lane LDS fragment bases (r&7 == lo&7 for all ti/tj)
    const int aOff0 = wm * 16384 + lo * 128 + offA;                 // + ti*2048
    const int bOff0 = (wn >> 1) * 16384 + ((wn & 1) * 64 + lo) * 128 + offA;

    const float ls = logit_scale[0];
    const int offs = offset[0];

    for (int zz = 0; zz < 2; ++zz) {
        const unsigned char* A = zz ? A1 : A0;
        const unsigned char* B = zz ? B1 : B0;
        float* S = zz ? S1 : S0;
        const unsigned char* Atile = A + (size_t)(2 * by) * kTiles * 16384;
        const unsigned char* Btile = B + (size_t)(2 * bx) * kTiles * 16384;

        f32x4 acc[8][4];
        #pragma unroll
        for (int i = 0; i < 8; ++i)
            #pragma unroll
            for (int j = 0; j < 4; ++j)
                acc[i][j] = (f32x4){0.f, 0.f, 0.f, 0.f};

        if (zz == 0) {                       // cold prologue (z0 only)
            stageOwner(0, Atile, Btile, 0);
            asm volatile("s_waitcnt vmcnt(0)" ::: "memory");
            __builtin_amdgcn_s_barrier();
        }
        // zz==1: tile0 was staged at z0's last K-tile and drained under
        // z0's epilogue; sits in buf0 (kTiles even -> parity matches).

        for (int kb = 0; kb < kTiles; ++kb) {
            const int cur = kb & 1;
            if (kb + 1 < kTiles) {
                stageOwner(1 - cur, Atile, Btile, kb + 1);
            } else if (zz == 0) {            // last tile of z0: stage z1 t0
                stageOwner(1 - cur,
                           A1 + (size_t)(2 * by) * kTiles * 16384,
                           B1 + (size_t)(2 * bx) * kTiles * 16384, 0);
            }

            i32x8 bq[4];
            #pragma unroll
            for (int tj = 0; tj < 4; ++tj) {
                const int ba = bOff0 + tj * 2048;
                union { int4 h[2]; i32x8 v; } u;
                u.h[0] = *(const int4*)&Bs[cur][ba];
                u.h[1] = *(const int4*)&Bs[cur][ba ^ 16];
                bq[tj] = u.v;
            }

            // One scheduler region: 16 ds_read_b128 + 32 MFMA; compiler
            // interleaves with fine lgkmcnt, waves drift -> LDS || MFMA.
            #pragma unroll
            for (int ph = 0; ph < 4; ++ph) {
                const int ti0 = 2 * ph;
                union { int4 h[2]; i32x8 v; } ua0, ua1;
                {
                    const int aa0 = aOff0 + ti0 * 2048;
                    ua0.h[0] = *(const int4*)&As[cur][aa0];
                    ua0.h[1] = *(const int4*)&As[cur][aa0 ^ 16];
                    const int aa1 = aOff0 + (ti0 + 1) * 2048;
                    ua1.h[0] = *(const int4*)&As[cur][aa1];
                    ua1.h[1] = *(const int4*)&As[cur][aa1 ^ 16];
                }
                #pragma unroll
                for (int tj = 0; tj < 4; ++tj)
                    acc[ti0][tj] = __builtin_amdgcn_mfma_scale_f32_16x16x128_f8f6f4(
                        ua0.v, bq[tj], acc[ti0][tj],
                        0, 0, 0, 127, 0, 127);
                #pragma unroll
                for (int tj = 0; tj < 4; ++tj)
                    acc[ti0 + 1][tj] = __builtin_amdgcn_mfma_scale_f32_16x16x128_f8f6f4(
                        ua1.v, bq[tj], acc[ti0 + 1][tj],
                        0, 0, 0, 127, 0, 127);
            }

            if (kb + 1 < kTiles) {
                // own DMA for kb+1 issued a full tile ago: cheap drain
                asm volatile("s_waitcnt vmcnt(0)" ::: "memory");
                __builtin_amdgcn_s_barrier();
            }
        }

        // epilogue for this z; z1's tile-0 DMA (if zz==0) flies under it
        const int rowBase = by * 256 + wm * 128;
        const int colBase = bx * 256 + wn * 64;
        #pragma unroll
        for (int ti = 0; ti < 8; ++ti) {
            #pragma unroll
            for (int r = 0; r < 4; ++r) {
                int gi = rowBase + 16 * ti + 4 * qd + r; // C/D row=quad*4+reg
                float rs = 0.f;
                #pragma unroll
                for (int tj = 0; tj < 4; ++tj) {
                    int gj = colBase + 16 * tj + lo;     // C/D col=lane&15
                    float e = __expf(ls * acc[ti][tj][r]);
                    if (gj == gi + offs) e = 0.f;        // shifted diagonal
                    rs += e;
                }
                #pragma unroll
                for (int m = 1; m < 16; m <<= 1) rs += __shfl_xor(rs, m, 64);
                if (lo == 0) atomicAdd(&S[gi], rs);
            }
        }

        if (zz == 0) {                       // drain z1 tile0 before z1 loop
            asm volatile("s_waitcnt vmcnt(0)" ::: "memory");
            __builtin_amdgcn_s_barrier();
        }
    }
}

// 32-block reduction; last block (ticket) computes the scalar loss.
__global__ __launch_bounds__(256) void final_kernel(
    const float* __restrict__ S_im, const float* __restrict__ S_tt,
    const float* __restrict__ diag,
    const float* __restrict__ ru_im, const float* __restrict__ ru_tt,
    const float* __restrict__ l1_im, const float* __restrict__ l1_tt,
    const float* __restrict__ u_im,  const float* __restrict__ u_tt,
    const float* __restrict__ logit_scale, float* __restrict__ red,
    float* __restrict__ out, int Bn)
{
    const float ls = logit_scale[0];
    const float inv_rw = 1.0f / (float)(Bn - 1);
    const int gid = blockIdx.x * 256 + threadIdx.x;
    const int stride = gridDim.x * 256;
    float pg = 0.f, lg = 0.f;
    for (int i = gid; i < Bn; i += stride) {
        float p1 = l1_im[i] / (u_im[i] + EPSF) + l1_tt[i] / (u_tt[i] + EPSF);
        float dd = expf(-ls * diag[i]);
        float p2 = dd * S_im[i] * inv_rw / (ru_im[i] + EPSF)
                 + dd * S_tt[i] * inv_rw / (ru_tt[i] + EPSF);
        pg += p1 + p2;
        lg += logf(u_im[i]) + logf(u_tt[i]);
    }
    __shared__ float sp[256], sl[256];
    sp[threadIdx.x] = pg; sl[threadIdx.x] = lg;
    __syncthreads();
    for (int s = 128; s > 0; s >>= 1) {
        if (threadIdx.x < s) { sp[threadIdx.x] += sp[threadIdx.x + s];
                               sl[threadIdx.x] += sl[threadIdx.x + s]; }
        __syncthreads();
    }
    if (threadIdx.x == 0) {
        atomicAdd(&red[0], sp[0]);
        atomicAdd(&red[1], sl[0]);
        __threadfence();
        int t = atomicAdd((int*)&red[2], 1);
        if (t == gridDim.x - 1) {
            float pgSum = atomicAdd(&red[0], 0.f);
            float lgSum = atomicAdd(&red[1], 0.f);
            float loss = ((pgSum / (float)Bn) * 0.5f) / ls
                       + RHOF / ls
                       + (lgSum / (float)Bn) * 0.5f / ls;
            out[0] = loss;
        }
    }
}

extern "C" void kernel_launch(void* const* d_in, const int* in_sizes, int n_in,
                              void* d_out, int out_size, void* d_ws, size_t ws_size,
                              hipStream_t stream) {
    const float* im    = (const float*)d_in[0];
    const float* tt    = (const float*)d_in[1];
    const float* rim   = (const float*)d_in[2];
    const float* rtt   = (const float*)d_in[3];
    const float* ru_im = (const float*)d_in[4];
    const float* ru_tt = (const float*)d_in[5];
    const float* l1_im = (const float*)d_in[6];
    const float* l1_tt = (const float*)d_in[7];
    const float* u_im  = (const float*)d_in[8];
    const float* u_tt  = (const float*)d_in[9];
    const float* lsc   = (const float*)d_in[10];
    const int*   offs  = (const int*)d_in[11];

    const int Bn = in_sizes[4];          // 4096
    const int D  = in_sizes[0] / Bn;     // 1024
    const int rpb = 4096 / D;            // rows per conversion block
    const int bpm = Bn / rpb;            // conversion blocks per matrix

    char* base = (char*)d_ws;
    float* S_im = (float*)base;
    float* S_tt = S_im + Bn;
    float* diag = S_tt + Bn;
    float* red  = diag + Bn;             // [0]=pg, [1]=lg, [2]=ticket
    const size_t headBytes = (((size_t)(3 * Bn + 8) * sizeof(float)) + 255) & ~(size_t)255;
    const size_t matBytes  = (size_t)Bn * D;          // fp8: 1 B/elem
    unsigned char* buf0 = (unsigned char*)(base + headBytes);
    unsigned char* bRim = buf0;
    unsigned char* bTt  = buf0 + matBytes;
    unsigned char* bRtt = buf0 + 2 * matBytes;
    unsigned char* bIm  = buf0 + 3 * matBytes;

    prep_fp8<<<4 * bpm + Bn / 4, 256, 0, stream>>>(
        im, tt, rim, rtt, bIm, bTt, bRim, bRtt, S_im, S_tt, diag, red, D, bpm);

    dim3 ggrid(Bn / 256, Bn / 256, 1);
    gemm_expsum<<<ggrid, 512, 0, stream>>>(bRim, bTt, S_im, bRtt, bIm, S_tt,
                                           lsc, offs, Bn, D);

    final_kernel<<<32, 256, 0, stream>>>(S_im, S_tt, diag, ru_im, ru_tt,
                                         l1_im, l1_tt, u_im, u_tt, lsc,
                                         red, (float*)d_out, Bn);
}